// Round 1
// baseline (1617.522 us; speedup 1.0000x reference)
//
#include <hip/hip_runtime.h>

// SimpleMinkUNet: 5 sparse convs (gather-GEMM-scatter) + 4 training-mode BN+ReLU.
// Output-stationary: per output row, binary-search each of the 27 sorted
// per-offset output lists; gather matching input rows; small GEMM in LDS.
// No atomics for conv; BN stats via double atomics.

constexpr int RT = 64;   // output rows per block
constexpr int MR = 4;    // rows per thread (register tile M)

template<int CIN, int COUT>
__global__ void sconv_kernel(const float* __restrict__ F, const float* __restrict__ W,
                             const int* __restrict__ II, const int* __restrict__ OO,
                             int P, const int* __restrict__ n_out_ptr,
                             float* __restrict__ OUT)
{
    constexpr int FS = CIN + 4;            // padded LDS f-row stride (bank-conflict dodge)
    constexpr int NLANE_C = COUT / 2;      // NR=2 couts per thread
    constexpr int NTHREADS = NLANE_C * (RT / MR);

    __shared__ int   s_in[27][RT];
    __shared__ float s_w[CIN * COUT];
    __shared__ float s_f[RT * FS];

    const int n_out = *n_out_ptr;
    const int row0 = blockIdx.x * RT;
    if (row0 >= n_out) return;             // uniform exit before any barrier
    const int tid = threadIdx.x;

    // ---- search phase: for each (k, row) find matching input index (or -1) ----
    for (int idx = tid; idx < 27 * RT; idx += NTHREADS) {
        int k = idx / RT;
        int r = idx - k * RT;
        int o = row0 + r;
        int found = -1;
        if (o < n_out) {
            const int* ok = OO + k * P;    // sorted ascending, pads == n_out
            int lo = 0, hi = P;
            while (lo < hi) {
                int mid = (lo + hi) >> 1;
                if (ok[mid] < o) lo = mid + 1; else hi = mid;
            }
            if (lo < P && ok[lo] == o) found = II[k * P + lo];
        }
        s_in[k][r] = found;
    }

    const int c2 = tid % NLANE_C;
    const int rg = tid / NLANE_C;
    const int c0 = c2 * 2;
    const int r0 = rg * MR;

    float acc[MR][2];
    #pragma unroll
    for (int m = 0; m < MR; ++m) { acc[m][0] = 0.f; acc[m][1] = 0.f; }

    for (int k = 0; k < 27; ++k) {
        __syncthreads();   // also covers search-phase visibility on k==0
        // stage W[k] slice (CIN*COUT contiguous floats)
        {
            const float4* wsrc = (const float4*)(W + k * CIN * COUT);
            float4* wdst = (float4*)s_w;
            for (int j = tid; j < (CIN * COUT) / 4; j += NTHREADS) wdst[j] = wsrc[j];
        }
        // gather input rows for this offset into LDS (zero-fill missing)
        {
            constexpr int F4 = CIN / 4;
            for (int j = tid; j < RT * F4; j += NTHREADS) {
                int r = j / F4;
                int q = j - r * F4;
                int in = s_in[k][r];
                float4 v = make_float4(0.f, 0.f, 0.f, 0.f);
                if (in >= 0) v = *(const float4*)(F + in * CIN + q * 4);
                *(float4*)&s_f[r * FS + q * 4] = v;
            }
        }
        __syncthreads();

        // skip offset if none of this thread's MR rows matched
        int4 pres = *(const int4*)&s_in[k][r0];
        if ((pres.x & pres.y & pres.z & pres.w) < 0) continue;

        #pragma unroll
        for (int ci = 0; ci < CIN; ci += 4) {
            float2 w0 = *(const float2*)&s_w[(ci + 0) * COUT + c0];
            float2 w1 = *(const float2*)&s_w[(ci + 1) * COUT + c0];
            float2 w2 = *(const float2*)&s_w[(ci + 2) * COUT + c0];
            float2 w3 = *(const float2*)&s_w[(ci + 3) * COUT + c0];
            #pragma unroll
            for (int m = 0; m < MR; ++m) {
                float4 fv = *(const float4*)&s_f[(r0 + m) * FS + ci];
                acc[m][0] += fv.x * w0.x + fv.y * w1.x + fv.z * w2.x + fv.w * w3.x;
                acc[m][1] += fv.x * w0.y + fv.y * w1.y + fv.z * w2.y + fv.w * w3.y;
            }
        }
    }

    #pragma unroll
    for (int m = 0; m < MR; ++m) {
        int o = row0 + r0 + m;
        if (o < n_out) {
            *(float2*)(OUT + o * COUT + c0) = make_float2(acc[m][0], acc[m][1]);
        }
    }
}

// ---- BN stats: per-channel sum & sumsq into double accumulators ----
template<int COUT, int BD>
__global__ void bn_reduce_kernel(const float* __restrict__ X, const int* __restrict__ n_ptr,
                                 double* __restrict__ sums)   // [0..C)=sum, [C..2C)=sumsq
{
    constexpr int G = BD / COUT;
    __shared__ float ls[BD], ls2[BD];
    const int n = *n_ptr;
    const int tid = threadIdx.x;
    const int c = tid % COUT;
    const int g = tid / COUT;
    float s = 0.f, s2 = 0.f;
    for (int r = blockIdx.x * G + g; r < n; r += gridDim.x * G) {
        float v = X[r * COUT + c];
        s += v; s2 += v * v;
    }
    ls[tid] = s; ls2[tid] = s2;
    __syncthreads();
    if (tid < COUT) {
        for (int j = tid + COUT; j < BD; j += COUT) { s += ls[j]; s2 += ls2[j]; }
        atomicAdd(&sums[c], (double)s);
        atomicAdd(&sums[COUT + c], (double)s2);
    }
}

// ---- normalize + ReLU in place ----
template<int COUT>
__global__ void bn_norm_relu_kernel(float* __restrict__ X, const int* __restrict__ n_ptr,
                                    const double* __restrict__ sums,
                                    const float* __restrict__ gamma,
                                    const float* __restrict__ beta)
{
    const int n = *n_ptr;
    const long total = (long)n * COUT;
    long idx = (long)blockIdx.x * blockDim.x + threadIdx.x;
    const long stride = (long)gridDim.x * blockDim.x;
    for (; idx < total; idx += stride) {
        int c = (int)(idx % COUT);
        double m  = sums[c] / n;
        double vv = sums[COUT + c] / n - m * m;
        float inv = (float)rsqrt(vv + 1e-5);
        float v = ((float)(X[idx] - (float)m)) * inv * gamma[c] + beta[c];
        X[idx] = v > 0.f ? v : 0.f;
    }
}

extern "C" void kernel_launch(void* const* d_in, const int* in_sizes, int n_in,
                              void* d_out, int out_size, void* d_ws, size_t ws_size,
                              hipStream_t stream)
{
    const float* feats = (const float*)d_in[0];
    const float* W0  = (const float*)d_in[1];
    const float* g0  = (const float*)d_in[2];
    const float* b0  = (const float*)d_in[3];
    const float* W1  = (const float*)d_in[4];
    const float* g1  = (const float*)d_in[5];
    const float* b1  = (const float*)d_in[6];
    const float* W2  = (const float*)d_in[7];
    const float* g2  = (const float*)d_in[8];
    const float* b2  = (const float*)d_in[9];
    const float* Wt1 = (const float*)d_in[10];
    const float* gt1 = (const float*)d_in[11];
    const float* bt1 = (const float*)d_in[12];
    const float* Wt2 = (const float*)d_in[13];
    const int* in0  = (const int*)d_in[14];
    const int* out0 = (const int*)d_in[15];
    const int* in1  = (const int*)d_in[16];
    const int* out1 = (const int*)d_in[17];
    const int* in2  = (const int*)d_in[18];
    const int* out2 = (const int*)d_in[19];
    const int* int1 = (const int*)d_in[20];
    const int* outt1= (const int*)d_in[21];
    const int* int2 = (const int*)d_in[22];
    const int* outt2= (const int*)d_in[23];
    const int* n0p = (const int*)d_in[24];
    const int* n1p = (const int*)d_in[25];
    const int* n2p = (const int*)d_in[26];

    const int n0  = in_sizes[0] / 4;       // 120000; n1,n2 <= n0 (device-side guards)
    const int P0  = in_sizes[14] / 27;
    const int P1  = in_sizes[16] / 27;
    const int P2  = in_sizes[18] / 27;
    const int Pt1 = in_sizes[20] / 27;
    const int Pt2 = in_sizes[22] / 27;

    // workspace layout (lifetime-aliased):
    //   [0,4096)                : BN double sums (4 regions x 1KB)
    //   A = ws+4096             : x1 (n0*32 f32)   [conv1..conv2], xt1 aliases [convt1..convt2]
    //   A + n0*32*4             : x2 (n0*64 f32)   [conv2..convt1], x0 (n0*16) aliases [conv0..conv1]
    char* ws = (char*)d_ws;
    double* sums0  = (double*)(ws + 0);
    double* sums1  = (double*)(ws + 1024);
    double* sums2  = (double*)(ws + 2048);
    double* sumst1 = (double*)(ws + 3072);
    float* x1  = (float*)(ws + 4096);
    float* x2  = x1 + (size_t)n0 * 32;
    float* x0  = x2;                       // aliases x2 region (dead before x2 written)
    float* xt1 = x1;                       // aliases x1 region (dead before xt1 written)
    float* out = (float*)d_out;

    const int gridC = (n0 + RT - 1) / RT;  // 1875 blocks; excess blocks exit on n check

    hipMemsetAsync(d_ws, 0, 4096, stream);

    // conv0: 4 -> 16, out rows n0
    sconv_kernel<4, 16><<<gridC, (16/2)*(RT/MR), 0, stream>>>(feats, W0, in0, out0, P0, n0p, x0);
    bn_reduce_kernel<16, 256><<<240, 256, 0, stream>>>(x0, n0p, sums0);
    bn_norm_relu_kernel<16><<<(n0 * 16 + 255) / 256, 256, 0, stream>>>(x0, n0p, sums0, g0, b0);

    // conv1: 16 -> 32, out rows n1
    sconv_kernel<16, 32><<<gridC, (32/2)*(RT/MR), 0, stream>>>(x0, W1, in1, out1, P1, n1p, x1);
    bn_reduce_kernel<32, 256><<<240, 256, 0, stream>>>(x1, n1p, sums1);
    bn_norm_relu_kernel<32><<<(n0 * 32 + 255) / 256, 256, 0, stream>>>(x1, n1p, sums1, g1, b1);

    // conv2: 32 -> 64, out rows n2
    sconv_kernel<32, 64><<<gridC, (64/2)*(RT/MR), 0, stream>>>(x1, W2, in2, out2, P2, n2p, x2);
    bn_reduce_kernel<64, 256><<<240, 256, 0, stream>>>(x2, n2p, sums2);
    bn_norm_relu_kernel<64><<<(n0 * 64 + 255) / 256, 256, 0, stream>>>(x2, n2p, sums2, g2, b2);

    // convtr1: 64 -> 32, out rows n1
    sconv_kernel<64, 32><<<gridC, (32/2)*(RT/MR), 0, stream>>>(x2, Wt1, int1, outt1, Pt1, n1p, xt1);
    bn_reduce_kernel<32, 256><<<240, 256, 0, stream>>>(xt1, n1p, sumst1);
    bn_norm_relu_kernel<32><<<(n0 * 32 + 255) / 256, 256, 0, stream>>>(xt1, n1p, sumst1, gt1, bt1);

    // convtr2: 32 -> 20, out rows n0, no BN
    sconv_kernel<32, 20><<<gridC, (20/2)*(RT/MR), 0, stream>>>(xt1, Wt2, int2, outt2, Pt2, n0p, out);
}